// Round 3
// baseline (1654.404 us; speedup 1.0000x reference)
//
#include <hip/hip_runtime.h>
#include <hip/hip_fp16.h>

#define TMAX 128

__device__ __forceinline__ float silu_f(float x) {
    return x / (1.f + __expf(-x));
}
__device__ __forceinline__ float softplus_f(float x) {
    return (x > 20.f) ? x : log1pf(__expf(x));
}

// ---------------- transpose in: x (B,C,H,W) -> xh (B,H,W,C) ----------------
__global__ __launch_bounds__(256) void k_tr_in(const float* __restrict__ x, float* __restrict__ xh) {
    __shared__ float tile[128 * 65];
    int h = blockIdx.x, b = blockIdx.y;
    const float* ip = x + (size_t)b * 64 * 16384 + (size_t)h * 128;
    for (int i = threadIdx.x; i < 64 * 128; i += 256) {
        int c = i >> 7, w = i & 127;
        tile[w * 65 + c] = ip[(size_t)c * 16384 + w];
    }
    __syncthreads();
    float* op = xh + ((size_t)(b * 128 + h)) * 128 * 64;
    for (int i = threadIdx.x; i < 128 * 64; i += 256) {
        int w = i >> 6, c = i & 63;
        op[i] = tile[w * 65 + c];
    }
}

// ---------------- transpose out: res (B,H,W,C) -> out (B,C,W,H) ----------------
__global__ __launch_bounds__(256) void k_tr_out(const float* __restrict__ res, float* __restrict__ out) {
    __shared__ float tile[64 * 129];
    int w = blockIdx.x, b = blockIdx.y;
    const float* ip = res + (size_t)b * 16384 * 64 + (size_t)w * 64;
    for (int i = threadIdx.x; i < 128 * 64; i += 256) {
        int h = i >> 6, c = i & 63;
        tile[c * 129 + h] = ip[(size_t)h * 128 * 64 + c];
    }
    __syncthreads();
    float* op = out + (size_t)b * 64 * 16384 + (size_t)w * 128;
    for (int i = threadIdx.x; i < 64 * 128; i += 256) {
        int c = i >> 7, hh = i & 127;
        op[(size_t)c * 16384 + hh] = tile[c * 129 + hh];
    }
}

// ---------------- downsample ----------------
__global__ __launch_bounds__(256) void k_down(const float* __restrict__ in, float* __restrict__ out,
                                              const float* __restrict__ dwp, int Ho, int Wo, int ntot) {
    __shared__ float dw[16384];
    for (int i = threadIdx.x; i < 16384; i += 256) {
        int o = i & 63, cpq = i >> 6;
        dw[cpq * 64 + o] = dwp[o * 256 + cpq];
    }
    __syncthreads();
    int gid = blockIdx.x * 256 + threadIdx.x;
    if (gid >= ntot) return;
    int og = gid & 3, pix = gid >> 2;
    int j = pix % Wo, i2 = (pix / Wo) % Ho, b = pix / (Wo * Ho);
    const float* ip = in + (((size_t)b * (2 * Ho) + 2 * i2) * (size_t)(2 * Wo) + 2 * j) * 64;
    float acc[16];
#pragma unroll
    for (int m = 0; m < 16; ++m) acc[m] = 0.f;
    for (int p = 0; p < 2; ++p) {
        for (int q = 0; q < 2; ++q) {
            const float* xp = ip + ((size_t)p * (2 * Wo) + q) * 64;
            for (int c = 0; c < 64; ++c) {
                float xv = xp[c];
                const float* wrow = &dw[(c * 4 + p * 2 + q) * 64 + og * 16];
#pragma unroll
                for (int m = 0; m < 16; ++m) acc[m] = fmaf(xv, wrow[m], acc[m]);
            }
        }
    }
    float* op = out + (size_t)pix * 64 + og * 16;
#pragma unroll
    for (int m = 0; m < 4; ++m) {
        float4 v = make_float4(acc[m * 4], acc[m * 4 + 1], acc[m * 4 + 2], acc[m * 4 + 3]);
        *(float4*)(op + m * 4) = v;
    }
}

// ---------------- upsample-accumulate ----------------
__global__ __launch_bounds__(256) void k_up(const float* __restrict__ src, float* __restrict__ dst,
                                            const float* __restrict__ uwp, int H, int W, float coef, int ntot) {
    __shared__ float uw[16384];
    for (int i = threadIdx.x; i < 16384; i += 256) {
        int o = i & 63, cpq = i >> 6;
        int c = cpq >> 2, pq = cpq & 3;
        uw[cpq * 64 + o] = uwp[c * 256 + o * 4 + pq];
    }
    __syncthreads();
    int gid = blockIdx.x * 256 + threadIdx.x;
    if (gid >= ntot) return;
    int og = gid & 3, pix = gid >> 2;
    int x = pix % W, y = (pix / W) % H, b = pix / (W * H);
    int Hs = H >> 1, Ws = W >> 1;
    int pq = (y & 1) * 2 + (x & 1);
    const float* sp = src + (((size_t)b * Hs + (y >> 1)) * (size_t)Ws + (x >> 1)) * 64;
    float acc[16];
#pragma unroll
    for (int m = 0; m < 16; ++m) acc[m] = 0.f;
    for (int c = 0; c < 64; ++c) {
        float xv = sp[c];
        const float* wrow = &uw[(c * 4 + pq) * 64 + og * 16];
#pragma unroll
        for (int m = 0; m < 16; ++m) acc[m] = fmaf(xv, wrow[m], acc[m]);
    }
    float* op = dst + (size_t)pix * 64 + og * 16;
#pragma unroll
    for (int m = 0; m < 4; ++m) {
        float4 cur = *(float4*)(op + m * 4);
        cur.x += coef * acc[m * 4];
        cur.y += coef * acc[m * 4 + 1];
        cur.z += coef * acc[m * 4 + 2];
        cur.w += coef * acc[m * 4 + 3];
        *(float4*)(op + m * 4) = cur;
    }
}

// ---------------- k_pre: LN + in_proj(xm) + conv + silu + x_proj + dt -> fp16 SoA streams
// stream layout (half2 units): plane p in [0,48): base (p*nseq+seqL)*n + t
//   p = d      (0..31): (dt[d], xm[d])
//   p = 32+s/2 (32..39): (B[2p'],B[2p'+1])
//   p = 40+s/2 (40..47): (C[2p'],C[2p'+1])
__global__ __launch_bounds__(256) void k_pre(const float* __restrict__ xh, __half2* __restrict__ stream,
                                             const float* __restrict__ lnw, const float* __restrict__ lnb,
                                             const float* __restrict__ in_proj_w, const float* __restrict__ conv_w,
                                             const float* __restrict__ conv_b, const float* __restrict__ x_proj_w,
                                             const float* __restrict__ dt_w, const float* __restrict__ dt_b,
                                             int n, int nseq, int seq_base) {
    __shared__ float pre[259][33];
    __shared__ float Wm[16][32];
    __shared__ float Wxp[32][33];
    __shared__ float cw[32][4];
    __shared__ float cb[32], dtw[32], dtb[32];
    __shared__ float lw[64], lb[64];
    const int tid = threadIdx.x;
    const int t0 = blockIdx.x * 256;
    const int seqL = blockIdx.y;
    const int seqG = seq_base + seqL;
    const int b = seqG >> 2, g = seqG & 3;

    for (int i = tid; i < 512; i += 256) Wm[i >> 5][i & 31] = in_proj_w[(i >> 5) * 64 + (i & 31)];
    for (int i = tid; i < 32 * 33; i += 256) Wxp[i / 33][i % 33] = x_proj_w[i];
    for (int i = tid; i < 128; i += 256) cw[i >> 2][i & 3] = conv_w[i];
    if (tid < 32) { cb[tid] = conv_b[tid]; dtw[tid] = dt_w[tid]; dtb[tid] = dt_b[tid]; }
    if (tid < 64) { lw[tid] = lnw[tid]; lb[tid] = lnb[tid]; }
    __syncthreads();

    const int Tcb = min(256, n - t0);
    const int rows = Tcb + 3;
    for (int r = tid; r < rows; r += 256) {
        int t = t0 + r - 3;
        if (t < 0) {
#pragma unroll
            for (int d = 0; d < 32; ++d) pre[r][d] = 0.f;
        } else {
            const float4* xp = (const float4*)(xh + ((size_t)b * n + t) * 64);
            float4 v[16];
            float s = 0.f;
#pragma unroll
            for (int i = 0; i < 16; ++i) { v[i] = xp[i]; s += v[i].x + v[i].y + v[i].z + v[i].w; }
            float m = s * (1.f / 64.f);
            float q = 0.f;
#pragma unroll
            for (int i = 0; i < 16; ++i) {
                float a = v[i].x - m, b2 = v[i].y - m, c = v[i].z - m, dd = v[i].w - m;
                q += a * a + b2 * b2 + c * c + dd * dd;
            }
            float rr = rsqrtf(q * (1.f / 64.f) + 1e-5f);
            const float4* xg = (const float4*)(xh + ((size_t)b * n + t) * 64 + g * 16);
            float xn16[16];
#pragma unroll
            for (int i = 0; i < 4; ++i) {
                float4 u4 = xg[i];
                int c0 = g * 16 + i * 4;
                xn16[i * 4 + 0] = (u4.x - m) * rr * lw[c0 + 0] + lb[c0 + 0];
                xn16[i * 4 + 1] = (u4.y - m) * rr * lw[c0 + 1] + lb[c0 + 1];
                xn16[i * 4 + 2] = (u4.z - m) * rr * lw[c0 + 2] + lb[c0 + 2];
                xn16[i * 4 + 3] = (u4.w - m) * rr * lw[c0 + 3] + lb[c0 + 3];
            }
#pragma unroll
            for (int d = 0; d < 32; ++d) {
                float a = 0.f;
#pragma unroll
                for (int j = 0; j < 16; ++j) a = fmaf(xn16[j], Wm[j][d], a);
                pre[r][d] = a;
            }
        }
    }
    __syncthreads();

    if (tid < Tcb) {
        const int t = t0 + tid;
        float xmv[32];
#pragma unroll
        for (int d = 0; d < 32; ++d) {
            float a = cb[d];
#pragma unroll
            for (int k = 0; k < 4; ++k) a = fmaf(pre[tid + k][d], cw[d][k], a);
            xmv[d] = silu_f(a);
        }
        float dtr = 0.f;
#pragma unroll
        for (int d = 0; d < 32; ++d) dtr = fmaf(xmv[d], Wxp[d][0], dtr);
        const size_t sb = (size_t)seqL * n + t;
#pragma unroll
        for (int d = 0; d < 32; ++d) {
            float dtv = softplus_f(fmaf(dtr, dtw[d], dtb[d]));
            stream[(size_t)d * nseq * n + sb] = __floats2half2_rn(dtv, xmv[d]);
        }
#pragma unroll
        for (int p = 0; p < 8; ++p) {
            float b0 = 0.f, b1 = 0.f;
#pragma unroll
            for (int d = 0; d < 32; ++d) {
                b0 = fmaf(xmv[d], Wxp[d][1 + 2 * p], b0);
                b1 = fmaf(xmv[d], Wxp[d][2 + 2 * p], b1);
            }
            stream[(size_t)(32 + p) * nseq * n + sb] = __floats2half2_rn(b0, b1);
        }
#pragma unroll
        for (int p = 0; p < 8; ++p) {
            float c0 = 0.f, c1 = 0.f;
#pragma unroll
            for (int d = 0; d < 32; ++d) {
                c0 = fmaf(xmv[d], Wxp[d][17 + 2 * p], c0);
                c1 = fmaf(xmv[d], Wxp[d][18 + 2 * p], c1);
            }
            stream[(size_t)(40 + p) * nseq * n + sb] = __floats2half2_rn(c0, c1);
        }
    }
}

// ---------------- k_scanA: per-chunk local scan -> P (chunk decay), H (chunk end-state) ----
__global__ __launch_bounds__(256) void k_scanA(const __half2* __restrict__ stream, float* __restrict__ P,
                                               float* __restrict__ H, const float* __restrict__ A_log,
                                               int n, int nseq, int nch) {
    const int tid = threadIdx.x;
    const int d = tid >> 3, ss = tid & 7;
    const int chunk = blockIdx.x, seqL = blockIdx.y;
    const int t0 = chunk * TMAX;
    const int Tc = min(TMAX, n - t0);
    const float a0 = -__expf(A_log[d * 16 + 2 * ss]);
    const float a1 = -__expf(A_log[d * 16 + 2 * ss + 1]);
    const __half2* pdx = stream + ((size_t)d * nseq + seqL) * n + t0;
    const __half2* pB = stream + ((size_t)(32 + ss) * nseq + seqL) * n + t0;
    float h0 = 0.f, h1 = 0.f, sdt = 0.f;
    for (int t = 0; t < Tc; ++t) {
        float2 dx = __half22float2(pdx[t]);
        float2 bv = __half22float2(pB[t]);
        float u = dx.x * dx.y;
        h0 = fmaf(__expf(a0 * dx.x), h0, u * bv.x);
        h1 = fmaf(__expf(a1 * dx.x), h1, u * bv.y);
        sdt += dx.x;
    }
    const size_t cbi = ((size_t)seqL * nch + chunk) * 512 + tid * 2;
    *(float2*)&P[cbi] = make_float2(__expf(a0 * sdt), __expf(a1 * sdt));
    *(float2*)&H[cbi] = make_float2(h0, h1);
}

// ---------------- k_scanB: sequential combine over chunks ----------------
__global__ __launch_bounds__(256) void k_scanB(const float* __restrict__ P, const float* __restrict__ Hl,
                                               float* __restrict__ hin, int nch, int nseq) {
    int idx = blockIdx.x * 256 + threadIdx.x;
    if (idx >= nseq * 512) return;
    int seq = idx >> 9, ds = idx & 511;
    size_t base = (size_t)seq * nch * 512 + ds;
    float h = 0.f;
    for (int k = 0; k < nch; ++k) {
        hin[base + (size_t)k * 512] = h;
        h = fmaf(P[base + (size_t)k * 512], h, Hl[base + (size_t)k * 512]);
    }
}

// ---------------- k_scanC: full scan + y + gate + out_proj + skip -> ym ----------------
__global__ __launch_bounds__(256) void k_scanC(const __half2* __restrict__ stream, const float* __restrict__ hin,
                                               const float* __restrict__ xh, float* __restrict__ ym,
                                               const float* __restrict__ A_log,
                                               const float* __restrict__ lnw, const float* __restrict__ lnb,
                                               const float* __restrict__ in_proj_w, const float* __restrict__ Dvec,
                                               const float* __restrict__ out_proj_w,
                                               const float* __restrict__ skip_scale,
                                               int n, int nseq, int seq_base, int nch) {
    __shared__ float yb[TMAX][33];
    __shared__ float Wz[16][32];
    __shared__ float Wout[32][16];
    __shared__ float lw[64], lb[64];
    __shared__ float Dsh[32];
    const int tid = threadIdx.x;
    const int d = tid >> 3, ss = tid & 7;
    const int chunk = blockIdx.x, seqL = blockIdx.y;
    const int seqG = seq_base + seqL;
    const int b = seqG >> 2, g = seqG & 3;
    const int t0 = chunk * TMAX;
    const int Tc = min(TMAX, n - t0);

    for (int i = tid; i < 512; i += 256) Wz[i >> 5][i & 31] = in_proj_w[(i >> 5) * 64 + 32 + (i & 31)];
    for (int i = tid; i < 512; i += 256) Wout[i >> 4][i & 15] = out_proj_w[i];
    if (tid < 64) { lw[tid] = lnw[tid]; lb[tid] = lnb[tid]; }
    if (tid < 32) Dsh[tid] = Dvec[tid];

    const float a0 = -__expf(A_log[d * 16 + 2 * ss]);
    const float a1 = -__expf(A_log[d * 16 + 2 * ss + 1]);
    const __half2* pdx = stream + ((size_t)d * nseq + seqL) * n + t0;
    const __half2* pB = stream + ((size_t)(32 + ss) * nseq + seqL) * n + t0;
    const __half2* pC = stream + ((size_t)(40 + ss) * nseq + seqL) * n + t0;
    const size_t cbi = ((size_t)seqL * nch + chunk) * 512 + tid * 2;
    float2 hi2 = *(const float2*)&hin[cbi];
    float h0 = hi2.x, h1 = hi2.y;

    for (int t = 0; t < Tc; ++t) {
        float2 dx = __half22float2(pdx[t]);
        float2 bv = __half22float2(pB[t]);
        float2 cv = __half22float2(pC[t]);
        float u = dx.x * dx.y;
        h0 = fmaf(__expf(a0 * dx.x), h0, u * bv.x);
        h1 = fmaf(__expf(a1 * dx.x), h1, u * bv.y);
        float pp = fmaf(h0, cv.x, h1 * cv.y);
        pp += __shfl_xor(pp, 1);
        pp += __shfl_xor(pp, 2);
        pp += __shfl_xor(pp, 4);
        if (ss == 0) yb[t][d] = pp;
    }
    __syncthreads();

    if (tid < Tc) {
        const int t = t0 + tid;
        const float4* xp = (const float4*)(xh + ((size_t)b * n + t) * 64);
        float4 v[16];
        float s = 0.f;
#pragma unroll
        for (int i = 0; i < 16; ++i) { v[i] = xp[i]; s += v[i].x + v[i].y + v[i].z + v[i].w; }
        float m = s * (1.f / 64.f);
        float q = 0.f;
#pragma unroll
        for (int i = 0; i < 16; ++i) {
            float a = v[i].x - m, b2 = v[i].y - m, c = v[i].z - m, dd = v[i].w - m;
            q += a * a + b2 * b2 + c * c + dd * dd;
        }
        float rr = rsqrtf(q * (1.f / 64.f) + 1e-5f);
        const float4* xg = (const float4*)(xh + ((size_t)b * n + t) * 64 + g * 16);
        float xc[16];
#pragma unroll
        for (int i = 0; i < 4; ++i) {
            float4 u4 = xg[i];
            int c0 = g * 16 + i * 4;
            xc[i * 4 + 0] = (u4.x - m) * rr * lw[c0 + 0] + lb[c0 + 0];
            xc[i * 4 + 1] = (u4.y - m) * rr * lw[c0 + 1] + lb[c0 + 1];
            xc[i * 4 + 2] = (u4.z - m) * rr * lw[c0 + 2] + lb[c0 + 2];
            xc[i * 4 + 3] = (u4.w - m) * rr * lw[c0 + 3] + lb[c0 + 3];
        }
        float yv[32];
#pragma unroll
        for (int dd = 0; dd < 32; ++dd) {
            float2 dx = __half22float2(stream[((size_t)dd * nseq + seqL) * n + t0 + tid]);
            float zz = 0.f;
#pragma unroll
            for (int j = 0; j < 16; ++j) zz = fmaf(xc[j], Wz[j][dd], zz);
            yv[dd] = (yb[tid][dd] + dx.y * Dsh[dd]) * silu_f(zz);
        }
        float sscale = skip_scale[0];
        float* ymtok = ym + ((size_t)b * n + t) * 64 + g * 16;
#pragma unroll
        for (int jq = 0; jq < 4; ++jq) {
            float o0 = 0.f, o1 = 0.f, o2 = 0.f, o3 = 0.f;
#pragma unroll
            for (int dd = 0; dd < 32; ++dd) {
                o0 = fmaf(yv[dd], Wout[dd][jq * 4 + 0], o0);
                o1 = fmaf(yv[dd], Wout[dd][jq * 4 + 1], o1);
                o2 = fmaf(yv[dd], Wout[dd][jq * 4 + 2], o2);
                o3 = fmaf(yv[dd], Wout[dd][jq * 4 + 3], o3);
            }
            float4 ov = make_float4(o0 + sscale * xc[jq * 4 + 0], o1 + sscale * xc[jq * 4 + 1],
                                    o2 + sscale * xc[jq * 4 + 2], o3 + sscale * xc[jq * 4 + 3]);
            *(float4*)(ymtok + jq * 4) = ov;
        }
    }
}

// ---------------- LN2 + proj (64x64) ----------------
__global__ __launch_bounds__(256) void k_post(const float* __restrict__ ym, float* __restrict__ outl,
                                              const float* __restrict__ lnw, const float* __restrict__ lnb,
                                              const float* __restrict__ proj_w, const float* __restrict__ proj_b,
                                              int ntok) {
    __shared__ float pw[4096];
    __shared__ float pb[64];
    __shared__ float lw[64], lb[64];
    for (int i = threadIdx.x; i < 4096; i += 256) pw[i] = proj_w[i];
    if (threadIdx.x < 64) {
        pb[threadIdx.x] = proj_b[threadIdx.x];
        lw[threadIdx.x] = lnw[threadIdx.x];
        lb[threadIdx.x] = lnb[threadIdx.x];
    }
    __syncthreads();
    int t = blockIdx.x * 256 + threadIdx.x;
    if (t >= ntok) return;
    const float4* p = (const float4*)(ym + (size_t)t * 64);
    float4 v[16];
    float s = 0.f;
#pragma unroll
    for (int i = 0; i < 16; ++i) {
        v[i] = p[i];
        s += v[i].x + v[i].y + v[i].z + v[i].w;
    }
    float m = s * (1.f / 64.f);
    float q = 0.f;
#pragma unroll
    for (int i = 0; i < 16; ++i) {
        float a = v[i].x - m, b2 = v[i].y - m, c = v[i].z - m, d = v[i].w - m;
        q += a * a + b2 * b2 + c * c + d * d;
    }
    float r = rsqrtf(q * (1.f / 64.f) + 1e-5f);
    float* op = outl + (size_t)t * 64;
    for (int half = 0; half < 2; ++half) {
        float acc[32];
#pragma unroll
        for (int o = 0; o < 32; ++o) acc[o] = pb[half * 32 + o];
#pragma unroll
        for (int i = 0; i < 16; ++i) {
            float vals[4] = {v[i].x, v[i].y, v[i].z, v[i].w};
#pragma unroll
            for (int k = 0; k < 4; ++k) {
                int c = i * 4 + k;
                float vn = (vals[k] - m) * r * lw[c] + lb[c];
                const float* wrow = &pw[c * 64 + half * 32];
#pragma unroll
                for (int o = 0; o < 32; ++o) acc[o] = fmaf(vn, wrow[o], acc[o]);
            }
        }
#pragma unroll
        for (int mq = 0; mq < 8; ++mq) {
            float4 ov = make_float4(acc[mq * 4], acc[mq * 4 + 1], acc[mq * 4 + 2], acc[mq * 4 + 3]);
            *(float4*)(op + half * 32 + mq * 4) = ov;
        }
    }
}

// ---------------- launcher ----------------
extern "C" void kernel_launch(void* const* d_in, const int* in_sizes, int n_in,
                              void* d_out, int out_size, void* d_ws, size_t ws_size,
                              hipStream_t stream_) {
    (void)in_sizes; (void)n_in; (void)out_size;
    const float* x          = (const float*)d_in[0];
    const float* ln_w       = (const float*)d_in[1];
    const float* ln_b       = (const float*)d_in[2];
    const float* skip_scale = (const float*)d_in[3];
    const float* proj_w     = (const float*)d_in[4];
    const float* proj_b     = (const float*)d_in[5];
    const float* in_proj_w  = (const float*)d_in[6];
    const float* conv_w     = (const float*)d_in[7];
    const float* conv_b     = (const float*)d_in[8];
    const float* x_proj_w   = (const float*)d_in[9];
    const float* dt_proj_w  = (const float*)d_in[10];
    const float* dt_proj_b  = (const float*)d_in[11];
    const float* A_log      = (const float*)d_in[12];
    const float* Dv         = (const float*)d_in[13];
    const float* out_proj_w = (const float*)d_in[14];
    const float* down_w     = (const float*)d_in[15];
    const float* up_w       = (const float*)d_in[16];
    float* out = (float*)d_out;
    float* ws = (float*)d_ws;

    static const int nl[5] = {16384, 4096, 1024, 256, 64};
    // float offsets
    static const size_t off_xh[5] = {0, 8388608, 10485760, 11010048, 11141120}; // end 11173888
    const size_t OFF_YM = 11173888;                                             // 8388608 (reused per level)
    static const size_t off_out[5] = {19562496, 27951104, 30048256, 30572544, 30703616}; // end 30736384
    const size_t OFF_P = 30736384, OFF_H = 32833536, OFF_HIN = 34930688;        // each 2097152
    const size_t STR_BYTE_OFF = 37027840ULL * 4ULL;                             // stream (fp16), reused per level
    __half2* strm = (__half2*)((char*)d_ws + STR_BYTE_OFF);

    // 1. transpose input
    k_tr_in<<<dim3(128, 8), dim3(256), 0, stream_>>>(x, ws + off_xh[0]);

    // 2. downsample chain
    for (int l = 0; l < 4; ++l) {
        int Ho = 128 >> (l + 1);
        int ntot = 8 * Ho * Ho * 4;
        k_down<<<dim3((ntot + 255) / 256), dim3(256), 0, stream_>>>(ws + off_xh[l], ws + off_xh[l + 1],
                                                                    down_w, Ho, Ho, ntot);
    }

    // 3. per-level mamba pipeline (stream buffer reused; seq-split if workspace tight)
    for (int l = 0; l < 5; ++l) {
        int n = nl[l];
        int ntok = 8 * n;
        int nch = (n + TMAX - 1) / TMAX;
        int nblk = (n + 255) / 256;
        int Sl = 1;
        while (Sl < 32 && STR_BYTE_OFF + (size_t)192 * (32 / Sl) * n > ws_size) Sl <<= 1;
        int nseq = 32 / Sl;
        for (int sp = 0; sp < Sl; ++sp) {
            int sb = sp * nseq;
            k_pre<<<dim3(nblk, nseq), dim3(256), 0, stream_>>>(ws + off_xh[l], strm, ln_w, ln_b, in_proj_w,
                                                               conv_w, conv_b, x_proj_w, dt_proj_w, dt_proj_b,
                                                               n, nseq, sb);
            k_scanA<<<dim3(nch, nseq), dim3(256), 0, stream_>>>(strm, ws + OFF_P, ws + OFF_H, A_log, n, nseq, nch);
            k_scanB<<<dim3(nseq * 2), dim3(256), 0, stream_>>>(ws + OFF_P, ws + OFF_H, ws + OFF_HIN, nch, nseq);
            k_scanC<<<dim3(nch, nseq), dim3(256), 0, stream_>>>(strm, ws + OFF_HIN, ws + off_xh[l], ws + OFF_YM,
                                                                A_log, ln_w, ln_b, in_proj_w, Dv, out_proj_w,
                                                                skip_scale, n, nseq, sb, nch);
        }
        k_post<<<dim3((ntok + 255) / 256), dim3(256), 0, stream_>>>(ws + OFF_YM, ws + off_out[l], ln_w, ln_b,
                                                                    proj_w, proj_b, ntok);
    }

    // 4. upsweep
    static const float coefs[4] = {1.f, 0.5f, 1.f / 3.f, 0.25f};
    for (int k = 0; k < 4; ++k) {
        int l = 3 - k;
        int H = 128 >> l;
        int ntot = 8 * H * H * 4;
        k_up<<<dim3((ntot + 255) / 256), dim3(256), 0, stream_>>>(ws + off_out[l + 1], ws + off_out[l],
                                                                  up_w, H, H, coefs[k], ntot);
    }

    // 5. final transpose
    k_tr_out<<<dim3(128, 8), dim3(256), 0, stream_>>>(ws + off_out[0], out);
}